// Round 4
// baseline (204.596 us; speedup 1.0000x reference)
//
#include <hip/hip_runtime.h>
#include <math.h>

#define BLOCK 256
#define QPT   4      // queries per thread in the two scan kernels
#define CHUNK 512    // refs staged per LDS chunk (8 KB of float4)
#define CAP   8      // candidate slots per query in recovery

// Rounding-exact helpers: match numpy's mul-then-add rounding exactly.
__device__ __forceinline__ float mul_rn(float a, float b) {
#pragma clang fp contract(off)
    return a * b;
}
__device__ __forceinline__ float add_rn(float a, float b) {
#pragma clang fp contract(off)
    return a + b;
}
__device__ __forceinline__ float sumsq3(float x, float y, float z) {
    return add_rn(add_rn(mul_rn(x, x), mul_rn(y, y)), mul_rn(z, z));
}
__device__ __forceinline__ float med3f(float a, float b, float c) {
    return __builtin_amdgcn_fmed3f(a, b, c);
}
// sq = (||a||^2 + ||b||^2) - 2*dot, dot as BLAS k-order fma chain; the
// -2*dot fold is single-rounded (2*dot exact) => bit-matches the reference.
__device__ __forceinline__ float pair_sq(float a0, float a1, float a2, float an,
                                         const float4& b) {
    const float dot = __builtin_fmaf(a2, b.z,
                      __builtin_fmaf(a1, b.y, mul_rn(a0, b.x)));
    return __builtin_fmaf(-2.0f, dot, add_rn(an, b.w));
}

// Stage cnt refs (cnt % 4 == 0, start % 4 == 0) into smem as (x,y,z,||b||^2).
__device__ __forceinline__ void stage_chunk(const float* __restrict__ r,
                                            int start, int cnt,
                                            float4* __restrict__ smem) {
    const int t = threadIdx.x;
    if (t < (cnt >> 2)) {
        const float4* p = (const float4*)(r + (size_t)(start + t * 4) * 3);
        const float4 A = p[0], B = p[1], C = p[2];
        smem[t * 4 + 0] = make_float4(A.x, A.y, A.z, sumsq3(A.x, A.y, A.z));
        smem[t * 4 + 1] = make_float4(A.w, B.x, B.y, sumsq3(A.w, B.x, B.y));
        smem[t * 4 + 2] = make_float4(B.z, B.w, C.x, sumsq3(B.z, B.w, C.x));
        smem[t * 4 + 3] = make_float4(C.y, C.z, C.w, sumsq3(C.y, C.z, C.w));
    }
}

__global__ __launch_bounds__(BLOCK) void zero_kernel(int* __restrict__ cnt, int n)
{
    const int i = blockIdx.x * BLOCK + threadIdx.x;
    if (i < n) cnt[i] = 0;
}

// Pass 1: branchless top-3 VALUES per (query, slice). 8 VALU/pair, no
// control flow in the inner loop -> fully pipelined ds_read batching.
__global__ __launch_bounds__(BLOCK) void values_kernel(
    const float* __restrict__ q, const float* __restrict__ r,
    float* __restrict__ vcand, int N, int refsPerSlice)
{
    __shared__ float4 smem[CHUNK];
    const int tid = threadIdx.x;
    const int start = blockIdx.y * refsPerSlice;

    float a0[QPT], a1[QPT], a2[QPT], an[QPT];
    float d0[QPT], d1[QPT], d2[QPT];
#pragma unroll
    for (int u = 0; u < QPT; ++u) {
        const int qi = (blockIdx.x * QPT + u) * BLOCK + tid;
        a0[u] = q[qi * 3 + 0];
        a1[u] = q[qi * 3 + 1];
        a2[u] = q[qi * 3 + 2];
        an[u] = sumsq3(a0[u], a1[u], a2[u]);
        d0[u] = __builtin_inff(); d1[u] = __builtin_inff(); d2[u] = __builtin_inff();
    }

    for (int coff = 0; coff < refsPerSlice; coff += CHUNK) {
        const int cnt = min(CHUNK, refsPerSlice - coff);
        __syncthreads();
        stage_chunk(r, start + coff, cnt, smem);
        __syncthreads();
#pragma unroll 4
        for (int j = 0; j < cnt; ++j) {
            const float4 b = smem[j];
#pragma unroll
            for (int u = 0; u < QPT; ++u) {
                const float sq = pair_sq(a0[u], a1[u], a2[u], an[u], b);
                const float t0 = d0[u], t1 = d1[u];
                d0[u] = fminf(t0, sq);
                d1[u] = med3f(t0, d1[u], sq);
                d2[u] = med3f(t1, d2[u], sq);
            }
        }
    }

#pragma unroll
    for (int u = 0; u < QPT; ++u) {
        const int qi = (blockIdx.x * QPT + u) * BLOCK + tid;
        float* o = vcand + ((size_t)blockIdx.y * N + qi) * 3;
        o[0] = d0[u]; o[1] = d1[u]; o[2] = d2[u];
    }
}

// Pass 2: d2q[qi] = global 3rd-smallest value (from union of slice top-3s).
__global__ __launch_bounds__(BLOCK) void bound_kernel(
    const float* __restrict__ vcand, float* __restrict__ d2q,
    int N, int slices)
{
    const int qi = blockIdx.x * BLOCK + threadIdx.x;
    float d0 = __builtin_inff(), d1 = __builtin_inff(), d2 = __builtin_inff();
    for (int s = 0; s < slices; ++s) {
        const float* c = vcand + ((size_t)s * N + qi) * 3;
#pragma unroll
        for (int k = 0; k < 3; ++k) {
            const float v = c[k];
            const float t0 = d0, t1 = d1;
            d0 = fminf(t0, v);
            d1 = med3f(t0, d1, v);
            d2 = med3f(t1, d2, v);
        }
    }
    d2q[qi] = d2;
}

// Pass 3: recovery. Re-derive sq (identical rounding => identical bits) and
// append indices with sq <= d2q (exactly the top-3 members, plus value-ties)
// via atomics. The atomic side effect forces the compiler to keep the rare
// path branched: hot loop is 6 VALU/pair + exec-mask scalar branches.
__global__ __launch_bounds__(BLOCK) void recover_kernel(
    const float* __restrict__ q, const float* __restrict__ r,
    const float* __restrict__ d2q, int* __restrict__ cnt,
    int* __restrict__ hits, int N, int refsPerSlice)
{
    __shared__ float4 smem[CHUNK];
    const int tid = threadIdx.x;
    const int start = blockIdx.y * refsPerSlice;

    float a0[QPT], a1[QPT], a2[QPT], an[QPT], bq[QPT];
    int qiu[QPT];
#pragma unroll
    for (int u = 0; u < QPT; ++u) {
        const int qi = (blockIdx.x * QPT + u) * BLOCK + tid;
        qiu[u] = qi;
        a0[u] = q[qi * 3 + 0];
        a1[u] = q[qi * 3 + 1];
        a2[u] = q[qi * 3 + 2];
        an[u] = sumsq3(a0[u], a1[u], a2[u]);
        bq[u] = d2q[qi];
    }

    for (int coff = 0; coff < refsPerSlice; coff += CHUNK) {
        const int cc = min(CHUNK, refsPerSlice - coff);
        __syncthreads();
        stage_chunk(r, start + coff, cc, smem);
        __syncthreads();
        const int base = start + coff;
#pragma unroll 4
        for (int j = 0; j < cc; ++j) {
            const float4 b = smem[j];
#pragma unroll
            for (int u = 0; u < QPT; ++u) {
                const float sq = pair_sq(a0[u], a1[u], a2[u], an[u], b);
                const bool c = sq <= bq[u];
                if (__ballot(c)) {
                    if (c) {
                        const int pos = atomicAdd(&cnt[qiu[u]], 1);
                        if (pos < CAP) hits[qiu[u] * CAP + pos] = base + j;
                    }
                }
            }
        }
    }
}

// Pass 4: per query, sort <=CAP candidates by exact (sq, idx) lexicographic
// (matches lax.top_k stability), then rounding-exact weights + flow gather.
__global__ __launch_bounds__(BLOCK) void final_kernel(
    const float* __restrict__ q, const float* __restrict__ r,
    const float* __restrict__ flow, const int* __restrict__ cnt,
    const int* __restrict__ hits, float* __restrict__ out, int N)
{
    const int qi = blockIdx.x * BLOCK + threadIdx.x;
    const float a0 = q[qi * 3 + 0];
    const float a1 = q[qi * 3 + 1];
    const float a2 = q[qi * 3 + 2];
    const float an = sumsq3(a0, a1, a2);

    float d0 = __builtin_inff(), d1 = __builtin_inff(), d2 = __builtin_inff();
    int   i0 = 0x7fffffff, i1 = 0x7fffffff, i2 = 0x7fffffff;

    const int c = min(cnt[qi], CAP);
    for (int t = 0; t < c; ++t) {
        const int idx = hits[qi * CAP + t];
        const float b0 = r[3 * idx + 0];
        const float b1 = r[3 * idx + 1];
        const float b2 = r[3 * idx + 2];
        const float4 b4 = make_float4(b0, b1, b2, sumsq3(b0, b1, b2));
        const float sq = pair_sq(a0, a1, a2, an, b4);
        const bool l0 = (sq < d0) || (sq == d0 && idx < i0);
        const bool l1 = (sq < d1) || (sq == d1 && idx < i1);
        const bool l2 = (sq < d2) || (sq == d2 && idx < i2);
        i2 = l1 ? i1 : (l2 ? idx : i2);
        d2 = l1 ? d1 : (l2 ? sq  : d2);
        i1 = l0 ? i0 : (l1 ? idx : i1);
        d1 = l0 ? d0 : (l1 ? sq  : d1);
        i0 = l0 ? idx : i0;
        d0 = l0 ? sq  : d0;
    }

    const float t0 = sqrtf(fmaxf(d0, 1e-12f));
    const float t1 = sqrtf(fmaxf(d1, 1e-12f));
    const float t2 = sqrtf(fmaxf(d2, 1e-12f));
    const float w0r = 1.0f / add_rn(t0, 1e-8f);
    const float w1r = 1.0f / add_rn(t1, 1e-8f);
    const float w2r = 1.0f / add_rn(t2, 1e-8f);
    const float wsum = add_rn(add_rn(w0r, w1r), w2r);
    const float w0 = w0r / wsum;
    const float w1 = w1r / wsum;
    const float w2 = w2r / wsum;

    const float f00 = flow[3 * i0 + 0], f01 = flow[3 * i0 + 1], f02 = flow[3 * i0 + 2];
    const float f10 = flow[3 * i1 + 0], f11 = flow[3 * i1 + 1], f12 = flow[3 * i1 + 2];
    const float f20 = flow[3 * i2 + 0], f21 = flow[3 * i2 + 1], f22 = flow[3 * i2 + 2];

    out[qi * 3 + 0] = add_rn(add_rn(mul_rn(w0, f00), mul_rn(w1, f10)), mul_rn(w2, f20));
    out[qi * 3 + 1] = add_rn(add_rn(mul_rn(w0, f01), mul_rn(w1, f11)), mul_rn(w2, f21));
    out[qi * 3 + 2] = add_rn(add_rn(mul_rn(w0, f02), mul_rn(w1, f12)), mul_rn(w2, f22));
}

extern "C" void kernel_launch(void* const* d_in, const int* in_sizes, int n_in,
                              void* d_out, int out_size, void* d_ws, size_t ws_size,
                              hipStream_t stream) {
    const float* q    = (const float*)d_in[0];
    const float* r    = (const float*)d_in[1];
    const float* flow = (const float*)d_in[2];
    // d_in[3] is k (==3), hard-coded.

    const int N = in_sizes[0] / 3;
    const int M = in_sizes[1] / 3;

    // ws layout: [vcand: S*N*3 f][d2q: N f][cnt: N i][hits: N*CAP i]
    const size_t tail = (size_t)N * sizeof(float) + (size_t)N * sizeof(int)
                      + (size_t)N * CAP * sizeof(int);
    int S = 64;
    while (S > 8 && (size_t)S * N * 3 * sizeof(float) + tail > ws_size) S >>= 1;
    const int refsPerSlice = M / S;

    float* vcand = (float*)d_ws;
    float* d2q   = (float*)((char*)d_ws + (size_t)S * N * 3 * sizeof(float));
    int*   cnt   = (int*)(d2q + N);
    int*   hits  = cnt + N;

    zero_kernel<<<(N + BLOCK - 1) / BLOCK, BLOCK, 0, stream>>>(cnt, N);

    dim3 grid(N / (BLOCK * QPT), S);
    values_kernel<<<grid, BLOCK, 0, stream>>>(q, r, vcand, N, refsPerSlice);
    bound_kernel<<<N / BLOCK, BLOCK, 0, stream>>>(vcand, d2q, N, S);
    recover_kernel<<<grid, BLOCK, 0, stream>>>(q, r, d2q, cnt, hits, N, refsPerSlice);
    final_kernel<<<N / BLOCK, BLOCK, 0, stream>>>(q, r, flow, cnt, hits,
                                                  (float*)d_out, N);
}

// Round 5
// 138.552 us; speedup vs baseline: 1.4767x; 1.4767x over previous
//
#include <hip/hip_runtime.h>
#include <math.h>

#define BLOCK 256
#define QPT   8      // queries per thread in the values pass
#define CHUNK 512    // refs staged per LDS chunk (8 KB of float4)

// Rounding-exact helpers: match numpy's mul-then-add rounding exactly.
__device__ __forceinline__ float mul_rn(float a, float b) {
#pragma clang fp contract(off)
    return a * b;
}
__device__ __forceinline__ float add_rn(float a, float b) {
#pragma clang fp contract(off)
    return a + b;
}
__device__ __forceinline__ float sumsq3(float x, float y, float z) {
    return add_rn(add_rn(mul_rn(x, x), mul_rn(y, y)), mul_rn(z, z));
}
__device__ __forceinline__ float med3f(float a, float b, float c) {
    return __builtin_amdgcn_fmed3f(a, b, c);
}
// sq = (||a||^2 + ||b||^2) - 2*dot, dot as BLAS k-order fma chain; the
// -2*dot fold is single-rounded (2*dot exact) => bit-matches the reference.
__device__ __forceinline__ float pair_sq(float a0, float a1, float a2, float an,
                                         float bx, float by, float bz, float bw) {
    const float dot = __builtin_fmaf(a2, bz,
                      __builtin_fmaf(a1, by, mul_rn(a0, bx)));
    return __builtin_fmaf(-2.0f, dot, add_rn(an, bw));
}

// Stage cnt refs (cnt % 4 == 0, start % 4 == 0) into smem as (x,y,z,||b||^2).
__device__ __forceinline__ void stage_chunk(const float* __restrict__ r,
                                            int start, int cnt,
                                            float4* __restrict__ smem) {
    const int t = threadIdx.x;
    if (t < (cnt >> 2)) {
        const float4* p = (const float4*)(r + (size_t)(start + t * 4) * 3);
        const float4 A = p[0], B = p[1], C = p[2];
        smem[t * 4 + 0] = make_float4(A.x, A.y, A.z, sumsq3(A.x, A.y, A.z));
        smem[t * 4 + 1] = make_float4(A.w, B.x, B.y, sumsq3(A.w, B.x, B.y));
        smem[t * 4 + 2] = make_float4(B.z, B.w, C.x, sumsq3(B.z, B.w, C.x));
        smem[t * 4 + 3] = make_float4(C.y, C.z, C.w, sumsq3(C.y, C.z, C.w));
    }
}

// Streaming top-3 VALUES update (exact selection, no arithmetic on values).
__device__ __forceinline__ void val3_push(float& d0, float& d1, float& d2, float v) {
    const float t0 = d0, t1 = d1;
    d0 = fminf(t0, v);
    d1 = med3f(t0, d1, v);
    d2 = med3f(t1, d2, v);
}

// Lexicographic (sq, idx) top-3 insert — matches lax.top_k stability.
__device__ __forceinline__ void lex3_push(float& d0, float& d1, float& d2,
                                          int& i0, int& i1, int& i2,
                                          float sq, int idx) {
    const bool l0 = (sq < d0) || (sq == d0 && idx < i0);
    const bool l1 = (sq < d1) || (sq == d1 && idx < i1);
    const bool l2 = (sq < d2) || (sq == d2 && idx < i2);
    i2 = l1 ? i1 : (l2 ? idx : i2);
    d2 = l1 ? d1 : (l2 ? sq  : d2);
    i1 = l0 ? i0 : (l1 ? idx : i1);
    d1 = l0 ? d0 : (l1 ? sq  : d1);
    i0 = l0 ? idx : i0;
    d0 = l0 ? sq  : d0;
}

// Pass 1: branchless top-3 VALUES per (query, slice). 8 VALU/pair, zero
// control flow in the inner loop. QPT=8 amortizes each ds_read_b128
// broadcast over 64 VALU wave-insts (LDS pipe at ~37% of VALU time).
__global__ __launch_bounds__(BLOCK) void values_kernel(
    const float* __restrict__ q, const float* __restrict__ r,
    float* __restrict__ vcand, int N, int refsPerSlice)
{
    __shared__ float4 smem[CHUNK];
    const int tid = threadIdx.x;
    const int start = blockIdx.y * refsPerSlice;

    float a0[QPT], a1[QPT], a2[QPT], an[QPT];
    float d0[QPT], d1[QPT], d2[QPT];
#pragma unroll
    for (int u = 0; u < QPT; ++u) {
        const int qi = (blockIdx.x * QPT + u) * BLOCK + tid;
        a0[u] = q[qi * 3 + 0];
        a1[u] = q[qi * 3 + 1];
        a2[u] = q[qi * 3 + 2];
        an[u] = sumsq3(a0[u], a1[u], a2[u]);
        d0[u] = __builtin_inff(); d1[u] = __builtin_inff(); d2[u] = __builtin_inff();
    }

    for (int coff = 0; coff < refsPerSlice; coff += CHUNK) {
        const int cnt = min(CHUNK, refsPerSlice - coff);
        __syncthreads();
        stage_chunk(r, start + coff, cnt, smem);
        __syncthreads();
#pragma unroll 2
        for (int j = 0; j < cnt; ++j) {
            const float4 b = smem[j];
#pragma unroll
            for (int u = 0; u < QPT; ++u) {
                const float sq = pair_sq(a0[u], a1[u], a2[u], an[u],
                                         b.x, b.y, b.z, b.w);
                val3_push(d0[u], d1[u], d2[u], sq);
            }
        }
    }

#pragma unroll
    for (int u = 0; u < QPT; ++u) {
        const int qi = (blockIdx.x * QPT + u) * BLOCK + tid;
        float* o = vcand + ((size_t)blockIdx.y * N + qi) * 3;
        o[0] = d0[u]; o[1] = d1[u]; o[2] = d2[u];
    }
}

// Pass 2: ONE WAVE PER QUERY.
//  A) lane s (< S) loads slice s's value triple; butterfly-reduce the global
//     top-3 values -> g2 (true 3rd-smallest sq, exact).
//  B) mask = ballot(slice_d0 <= g2): a slice can contain a global top-3
//     member only if its min <= g2. Lanes cooperatively rescan just those
//     slices (typically ~3 of 64), tracking (sq, idx) per lane with strict <
//     (per-lane index order is ascending), then a lexicographic butterfly
//     merge reproduces lax.top_k's lowest-index tie-break exactly.
//  C) lane 0: rounding-exact weights + flow gather + store.
__global__ __launch_bounds__(BLOCK) void rescan_kernel(
    const float* __restrict__ q, const float* __restrict__ r,
    const float* __restrict__ vcand, const float* __restrict__ flow,
    float* __restrict__ out, int N, int S, int refsPerSlice)
{
    const int lane = threadIdx.x & 63;
    const int qi   = blockIdx.x * (BLOCK / 64) + (threadIdx.x >> 6);

    const float a0 = q[qi * 3 + 0];
    const float a1 = q[qi * 3 + 1];
    const float a2 = q[qi * 3 + 2];
    const float an = sumsq3(a0, a1, a2);

    // --- A: global top-3 values from per-slice triples ---
    float g0 = __builtin_inff(), g1 = __builtin_inff(), g2 = __builtin_inff();
    float sd0 = __builtin_inff();
    if (lane < S) {
        const float* c = vcand + ((size_t)lane * N + qi) * 3;
        const float v0 = c[0], v1 = c[1], v2 = c[2];
        sd0 = v0;
        val3_push(g0, g1, g2, v0);
        val3_push(g0, g1, g2, v1);
        val3_push(g0, g1, g2, v2);
    }
#pragma unroll
    for (int m = 1; m < 64; m <<= 1) {
        const float e0 = __shfl_xor(g0, m);
        const float e1 = __shfl_xor(g1, m);
        const float e2 = __shfl_xor(g2, m);
        val3_push(g0, g1, g2, e0);
        val3_push(g0, g1, g2, e1);
        val3_push(g0, g1, g2, e2);
    }

    unsigned long long mask = __ballot(sd0 <= g2);

    // --- B: cooperative rescan of contributing slices ---
    float d0 = __builtin_inff(), d1 = __builtin_inff(), d2 = __builtin_inff();
    int   i0 = 0x7fffffff, i1 = 0x7fffffff, i2 = 0x7fffffff;
    const int K = refsPerSlice >> 6;     // refs per lane per slice

    while (mask) {
        const int s = (int)__builtin_ctzll(mask);
        mask &= mask - 1;
        const int base = s * refsPerSlice;
        for (int k = 0; k < K; ++k) {
            const int idx = base + lane + (k << 6);
            const float b0 = r[3 * idx + 0];
            const float b1 = r[3 * idx + 1];
            const float b2 = r[3 * idx + 2];
            const float bw = sumsq3(b0, b1, b2);
            const float sq = pair_sq(a0, a1, a2, an, b0, b1, b2, bw);
            // strict <: per-lane stream is ascending-idx, earliest wins
            const bool c0 = sq < d0;
            const bool c1 = sq < d1;
            const bool c2 = sq < d2;
            i2 = c1 ? i1 : (c2 ? idx : i2);
            d2 = c1 ? d1 : (c2 ? sq  : d2);
            i1 = c0 ? i0 : (c1 ? idx : i1);
            d1 = c0 ? d0 : (c1 ? sq  : d1);
            i0 = c0 ? idx : i0;
            d0 = c0 ? sq  : d0;
        }
    }

    // lexicographic butterfly merge (disjoint lane blocks at every stage)
#pragma unroll
    for (int m = 1; m < 64; m <<= 1) {
        const float e0 = __shfl_xor(d0, m);
        const float e1 = __shfl_xor(d1, m);
        const float e2 = __shfl_xor(d2, m);
        const int   j0 = __shfl_xor(i0, m);
        const int   j1 = __shfl_xor(i1, m);
        const int   j2 = __shfl_xor(i2, m);
        lex3_push(d0, d1, d2, i0, i1, i2, e0, j0);
        lex3_push(d0, d1, d2, i0, i1, i2, e1, j1);
        lex3_push(d0, d1, d2, i0, i1, i2, e2, j2);
    }

    // --- C: epilogue (rounding-exact, matches reference op order) ---
    if (lane == 0) {
        const float t0 = sqrtf(fmaxf(d0, 1e-12f));
        const float t1 = sqrtf(fmaxf(d1, 1e-12f));
        const float t2 = sqrtf(fmaxf(d2, 1e-12f));
        const float w0r = 1.0f / add_rn(t0, 1e-8f);
        const float w1r = 1.0f / add_rn(t1, 1e-8f);
        const float w2r = 1.0f / add_rn(t2, 1e-8f);
        const float wsum = add_rn(add_rn(w0r, w1r), w2r);
        const float w0 = w0r / wsum;
        const float w1 = w1r / wsum;
        const float w2 = w2r / wsum;

        const float f00 = flow[3 * i0 + 0], f01 = flow[3 * i0 + 1], f02 = flow[3 * i0 + 2];
        const float f10 = flow[3 * i1 + 0], f11 = flow[3 * i1 + 1], f12 = flow[3 * i1 + 2];
        const float f20 = flow[3 * i2 + 0], f21 = flow[3 * i2 + 1], f22 = flow[3 * i2 + 2];

        out[qi * 3 + 0] = add_rn(add_rn(mul_rn(w0, f00), mul_rn(w1, f10)), mul_rn(w2, f20));
        out[qi * 3 + 1] = add_rn(add_rn(mul_rn(w0, f01), mul_rn(w1, f11)), mul_rn(w2, f21));
        out[qi * 3 + 2] = add_rn(add_rn(mul_rn(w0, f02), mul_rn(w1, f12)), mul_rn(w2, f22));
    }
}

extern "C" void kernel_launch(void* const* d_in, const int* in_sizes, int n_in,
                              void* d_out, int out_size, void* d_ws, size_t ws_size,
                              hipStream_t stream) {
    const float* q    = (const float*)d_in[0];
    const float* r    = (const float*)d_in[1];
    const float* flow = (const float*)d_in[2];
    // d_in[3] is k (==3), hard-coded.

    const int N = in_sizes[0] / 3;
    const int M = in_sizes[1] / 3;

    // ws layout: [vcand: S*N*3 floats], S in {64, 32} (<=64 for ballot mask)
    int S = 64;
    while (S > 8 && (size_t)S * N * 3 * sizeof(float) > ws_size) S >>= 1;
    const int refsPerSlice = M / S;

    float* vcand = (float*)d_ws;

    dim3 grid1(N / (BLOCK * QPT), S);
    values_kernel<<<grid1, BLOCK, 0, stream>>>(q, r, vcand, N, refsPerSlice);

    rescan_kernel<<<N / (BLOCK / 64), BLOCK, 0, stream>>>(
        q, r, vcand, flow, (float*)d_out, N, S, refsPerSlice);
}